// Round 8
// baseline (471.735 us; speedup 1.0000x reference)
//
#include <hip/hip_runtime.h>

#define DIMC 3072
#define NH 24
#define HD 128
#define QKV_N 9216
#define S_TXT 256
#define S_IMG 2048
#define S_TOT 2304

typedef _Float16 f16x8 __attribute__((ext_vector_type(8)));
typedef _Float16 f16x4 __attribute__((ext_vector_type(4)));
typedef _Float16 f16x2 __attribute__((ext_vector_type(2)));
typedef float f32x4 __attribute__((ext_vector_type(4)));

#define MFMA(A, B, C) __builtin_amdgcn_mfma_f32_16x16x32_f16(A, B, C, 0, 0, 0)

// scale(1/sqrt(128)) * log2(e): scores computed directly in log2 domain
#define QSCALE (0.08838834764831845f * 1.4426950408889634f)

// direct global->LDS async copy, 16B per lane; lds base must be wave-uniform
__device__ __forceinline__ void gl2lds16(const _Float16* g, _Float16* l) {
    __builtin_amdgcn_global_load_lds(
        (const __attribute__((address_space(1))) unsigned int*)g,
        (__attribute__((address_space(3))) unsigned int*)l,
        16, 0, 0);
}

// ---------------------------------------------------------------------------
// concat(enc,hid) -> fp16 (hi only)
// ---------------------------------------------------------------------------
__global__ __launch_bounds__(256) void split_x(
    const float* __restrict__ enc, const float* __restrict__ hid,
    _Float16* __restrict__ xh)
{
    const int s = blockIdx.x;
    const float* src = (s < S_TXT) ? enc + (size_t)s * DIMC
                                   : hid + (size_t)(s - S_TXT) * DIMC;
    const int t = threadIdx.x;
#pragma unroll
    for (int it = 0; it < 3; ++it) {
        const int i = (it * 256 + t) * 4;
        float4 v = *(const float4*)(src + i);
        f16x4 hv;
        hv.x = (_Float16)v.x; hv.y = (_Float16)v.y;
        hv.z = (_Float16)v.z; hv.w = (_Float16)v.w;
        *(f16x4*)(xh + (size_t)s * DIMC + i) = hv;
    }
}

// ---------------------------------------------------------------------------
// W [3072 k][ldw] f32 -> Wt [n][3072 k] fp16 (hi only)
// ---------------------------------------------------------------------------
__global__ __launch_bounds__(256) void transpose_w_hi(
    const float* __restrict__ W, const int ldw, _Float16* __restrict__ Th)
{
    __shared__ float T[64][68];
    const int n0 = blockIdx.x * 64, k0 = blockIdx.y * 64;
    const int t = threadIdx.x;
    {
        const int r = t >> 2, c4 = (t & 3) * 16;
#pragma unroll
        for (int j = 0; j < 4; ++j) {
            float4 v = *(const float4*)(W + (size_t)(k0 + r) * ldw + n0 + c4 + j * 4);
            *(float4*)&T[r][c4 + j * 4] = v;
        }
    }
    __syncthreads();
    const int nr = t >> 2, kp = (t & 3) * 16;
    f16x8 hv0, hv1;
#pragma unroll
    for (int j = 0; j < 8; ++j) hv0[j] = (_Float16)T[kp + j][nr];
#pragma unroll
    for (int j = 0; j < 8; ++j) hv1[j] = (_Float16)T[kp + 8 + j][nr];
    _Float16* dh = Th + (size_t)(n0 + nr) * DIMC + k0 + kp;
    *(f16x8*)(dh) = hv0; *(f16x8*)(dh + 8) = hv1;
}

// ---------------------------------------------------------------------------
// 8-phase 256x256 fp16 GEMM (QKV): C = A @ B^T + bias.
// 512 thr / 8 waves (2M x 4N), BK=64, 128KB LDS (2 dbuf x 2 halves x A,B).
// Per K-tile: 4 phases {12 ds_read + prefetch -> s_barrier -> 16 MFMA},
// prefetch tile T+1 issued phase 0 into other buffer, drained at boundary.
// Granule-XOR swizzle both-sides (0-conflict recipe from R6).
// ---------------------------------------------------------------------------
__global__ __launch_bounds__(512, 2) void gemm_f16_8ph(
    const _Float16* __restrict__ Ah, const _Float16* __restrict__ Bh,
    const float* __restrict__ bias, float* __restrict__ C)
{
    // A: halfwords [0, 32768): region (d*2+h)*8192 = [128 rows][64 k]
    // B: halfwords [32768, 65536): same structure
    __shared__ __attribute__((aligned(16))) _Float16 lds[65536];

    // bijective XCD swizzle for 324 blocks (324 = 8*40 + 4)
    const int orig = blockIdx.x;
    const int xcd = orig & 7, bidx = orig >> 3;
    const int wgid = (xcd < 4 ? xcd * 41 : 164 + (xcd - 4) * 40) + bidx;
    const int bm = (wgid % 9) * 256;
    const int bn = (wgid / 9) * 256;

    const int tid = threadIdx.x;
    const int l = tid & 63, wid = tid >> 6;
    const int wm = wid >> 2, wn = wid & 3;
    const int lr = l & 15, g = l >> 4;
    const int lx = lr & 7;

    // staging geometry: half-tile = 128 rows x 64 k; thread covers
    // idx = j*512 + tid (j=0,1): row = idx>>3, slot s = idx&7;
    // source k-slot = s ^ (row&7); LDS dest linear (wave-uniform + lane*16B)
    const int srow = tid >> 3;            // j=0 row (0..63); j=1 adds 64
    const int sslot = tid & 7;
    const int ldsl = (tid & 448) * 8;     // wid*64*8 halfwords

    const _Float16* gA[2] = { Ah + (size_t)(bm + srow) * DIMC,
                              Ah + (size_t)(bm + 128 + srow) * DIMC };
    const _Float16* gB[2] = { Bh + (size_t)(bn + srow) * DIMC,
                              Bh + (size_t)(bn + 128 + srow) * DIMC };
    const int swz0 = ((sslot ^ (srow & 7)) * 8);          // j=0
    const int swz1 = ((sslot ^ ((srow + 64) & 7)) * 8);   // j=1

#define STAGE_TILE(dst, k0) do { \
    _Float16* base = &lds[(dst) * 2 * 8192]; \
    gl2lds16(gA[0] + (k0) + swz0, base + ldsl); \
    gl2lds16(gA[0] + (size_t)64 * DIMC + (k0) + swz1, base + 4096 + ldsl); \
    gl2lds16(gA[1] + (k0) + swz0, base + 8192 + ldsl); \
    gl2lds16(gA[1] + (size_t)64 * DIMC + (k0) + swz1, base + 12288 + ldsl); \
    gl2lds16(gB[0] + (k0) + swz0, base + 32768 + ldsl); \
    gl2lds16(gB[0] + (size_t)64 * DIMC + (k0) + swz1, base + 36864 + ldsl); \
    gl2lds16(gB[1] + (k0) + swz0, base + 40960 + ldsl); \
    gl2lds16(gB[1] + (size_t)64 * DIMC + (k0) + swz1, base + 45056 + ldsl); \
} while (0)

    f32x4 acc[8][4] = {};

#define PHASE(d, qd) do { \
    const int ab = ((d) * 2 + wm) * 8192; \
    const int bb = 32768 + ((d) * 2 + (wn >> 1)) * 8192; \
    f16x8 bf0[4], bf1[4]; \
    _Pragma("unroll") \
    for (int ni = 0; ni < 4; ++ni) { \
        const int colp = (wn & 1) * 64 + ni * 16 + lr; \
        bf0[ni] = *(const f16x8*)&lds[bb + colp * 64 + ((g ^ lx) * 8)]; \
        bf1[ni] = *(const f16x8*)&lds[bb + colp * 64 + (((4 + g) ^ lx) * 8)]; \
    } \
    const int rp0 = ((qd) * 2 + 0) * 16 + lr; \
    const int rp1 = ((qd) * 2 + 1) * 16 + lr; \
    f16x8 a00 = *(const f16x8*)&lds[ab + rp0 * 64 + ((g ^ lx) * 8)]; \
    f16x8 a01 = *(const f16x8*)&lds[ab + rp0 * 64 + (((4 + g) ^ lx) * 8)]; \
    f16x8 a10 = *(const f16x8*)&lds[ab + rp1 * 64 + ((g ^ lx) * 8)]; \
    f16x8 a11 = *(const f16x8*)&lds[ab + rp1 * 64 + (((4 + g) ^ lx) * 8)]; \
    __builtin_amdgcn_s_setprio(1); \
    _Pragma("unroll") \
    for (int ni = 0; ni < 4; ++ni) { \
        acc[(qd) * 2 + 0][ni] = MFMA(a00, bf0[ni], acc[(qd) * 2 + 0][ni]); \
        acc[(qd) * 2 + 0][ni] = MFMA(a01, bf1[ni], acc[(qd) * 2 + 0][ni]); \
        acc[(qd) * 2 + 1][ni] = MFMA(a10, bf0[ni], acc[(qd) * 2 + 1][ni]); \
        acc[(qd) * 2 + 1][ni] = MFMA(a11, bf1[ni], acc[(qd) * 2 + 1][ni]); \
    } \
    __builtin_amdgcn_s_setprio(0); \
} while (0)

    // prologue: stage tile 0 into buf 0, full drain
    STAGE_TILE(0, 0);
    __syncthreads();

    for (int T = 0; T < DIMC / 64; ++T) {
        const int d = T & 1;
        // phase 0: prefetch tile T+1 into the other buffer, then quadrant 0
        if (T + 1 < DIMC / 64) STAGE_TILE(d ^ 1, (T + 1) * 64);
        PHASE(d, 0);
        __builtin_amdgcn_s_barrier();
        PHASE(d, 1);
        __builtin_amdgcn_s_barrier();
        PHASE(d, 2);
        __builtin_amdgcn_s_barrier();
        PHASE(d, 3);
        // boundary: drain prefetch (tile T+1) + full barrier
        asm volatile("s_waitcnt vmcnt(0)" ::: "memory");
        __syncthreads();
    }
#undef PHASE
#undef STAGE_TILE

#pragma unroll
    for (int mi = 0; mi < 8; ++mi)
#pragma unroll
        for (int ni = 0; ni < 4; ++ni) {
            const int cl = bn + wn * 64 + ni * 16 + lr;
            const float bv = bias[cl];
#pragma unroll
            for (int e = 0; e < 4; ++e) {
                const int r = bm + wm * 128 + mi * 16 + g * 4 + e;
                C[(size_t)r * QKV_N + cl] = acc[mi][ni][e] + bv;
            }
        }
}

// ---------------------------------------------------------------------------
// m97-structure fp16 GEMM (out-proj): 128x128, 2-phase, T1+T2 (R6-verified).
// ---------------------------------------------------------------------------
template <int REMAP>
__global__ __launch_bounds__(256) void gemm_f16_lds(
    const _Float16* __restrict__ Ah, const _Float16* __restrict__ Bh,
    const float* __restrict__ bias, float* __restrict__ C,
    const int nblk_m, const int ldc)
{
    __shared__ __attribute__((aligned(16))) _Float16 Ash[128 * 32];
    __shared__ __attribute__((aligned(16))) _Float16 Bsh[128 * 32];

    const int cpx = (int)gridDim.x >> 3;
    const int wgid = (blockIdx.x & 7) * cpx + (blockIdx.x >> 3);
    const int bm = (wgid % nblk_m) * 128;
    const int bn = (wgid / nblk_m) * 128;

    const int tid = threadIdx.x;
    const int l = tid & 63, w = tid >> 6;
    const int wr = w >> 1, wc = w & 1;
    const int lr = l & 15, g = l >> 4;

    const int srow0 = w * 32 + (l >> 2);
    const int srow1 = srow0 + 16;
    const int skp0 = (((l & 3) ^ ((srow0 >> 1) & 3)) * 8);
    const int skp1 = (((l & 3) ^ ((srow1 >> 1) & 3)) * 8);
    const _Float16* gA0 = Ah + (size_t)(bm + srow0) * DIMC + skp0;
    const _Float16* gA1 = Ah + (size_t)(bm + srow1) * DIMC + skp1;
    const _Float16* gB0 = Bh + (size_t)(bn + srow0) * DIMC + skp0;
    const _Float16* gB1 = Bh + (size_t)(bn + srow1) * DIMC + skp1;
    _Float16* lA0 = &Ash[(w * 32) * 32];
    _Float16* lA1 = &Ash[(w * 32 + 16) * 32];
    _Float16* lB0 = &Bsh[(w * 32) * 32];
    _Float16* lB1 = &Bsh[(w * 32 + 16) * 32];

    int aoff[4], boff[4];
#pragma unroll
    for (int i = 0; i < 4; ++i) {
        const int ra = wr * 64 + i * 16 + lr;
        const int rb = wc * 64 + i * 16 + lr;
        aoff[i] = ra * 32 + ((g ^ ((ra >> 1) & 3)) * 8);
        boff[i] = rb * 32 + ((g ^ ((rb >> 1) & 3)) * 8);
    }

    f32x4 acc[4][4] = {};

    for (int k0 = 0; k0 < DIMC; k0 += 32) {
        gl2lds16(gA0 + k0, lA0);
        gl2lds16(gA1 + k0, lA1);
        gl2lds16(gB0 + k0, lB0);
        gl2lds16(gB1 + k0, lB1);
        __syncthreads();

        f16x8 bhf[4];
#pragma unroll
        for (int ni = 0; ni < 4; ++ni)
            bhf[ni] = *(const f16x8*)&Bsh[boff[ni]];
#pragma unroll
        for (int mi = 0; mi < 4; ++mi) {
            f16x8 ahf = *(const f16x8*)&Ash[aoff[mi]];
#pragma unroll
            for (int ni = 0; ni < 4; ++ni)
                acc[mi][ni] = MFMA(ahf, bhf[ni], acc[mi][ni]);
        }
        __syncthreads();
    }

#pragma unroll
    for (int mi = 0; mi < 4; ++mi)
#pragma unroll
        for (int ni = 0; ni < 4; ++ni) {
            const int cl = bn + wc * 64 + ni * 16 + lr;
            const float bv = bias[cl];
#pragma unroll
            for (int e = 0; e < 4; ++e) {
                const int r = bm + wr * 64 + mi * 16 + g * 4 + e;
                if (REMAP) {
                    const int gr = (r < S_TXT) ? (S_IMG + r) : (r - S_TXT);
                    C[(size_t)gr * DIMC + cl] = acc[mi][ni][e] + bv;
                } else {
                    C[(size_t)r * ldc + cl] = acc[mi][ni][e] + bv;
                }
            }
        }
}

// ---------------------------------------------------------------------------
// LayerNorm + RoPE; Q is pre-scaled by scale*log2(e). fp16 out [NH][S][128].
// ---------------------------------------------------------------------------
__global__ __launch_bounds__(256) void ln_rope_split(
    const float* __restrict__ qkv,
    const float* __restrict__ cost, const float* __restrict__ sint,
    _Float16* __restrict__ Qh, _Float16* __restrict__ Kh)
{
    const int wave = threadIdx.x >> 6;
    const int lane = threadIdx.x & 63;
    const int task = blockIdx.x * 4 + wave;
    const int s = task / 48;
    const int rem = task % 48;
    const int qk = rem / 24;
    const int h = rem % 24;

    const float* p = qkv + (size_t)s * QKV_N + qk * DIMC + h * HD;
    float2 x = *(const float2*)(p + lane * 2);

    float sum = x.x + x.y;
    float sq = x.x * x.x + x.y * x.y;
#pragma unroll
    for (int off = 1; off < 64; off <<= 1) {
        sum += __shfl_xor(sum, off, 64);
        sq  += __shfl_xor(sq, off, 64);
    }
    const float mu = sum * (1.0f / 128.0f);
    const float var = sq * (1.0f / 128.0f) - mu * mu;
    const float rstd = rsqrtf(var + 1e-5f);
    float y0 = (x.x - mu) * rstd;
    float y1 = (x.y - mu) * rstd;

    if (s >= S_TXT) {
        const int ip = s - S_TXT;
        const float c = cost[ip * 64 + lane];
        const float sn = sint[ip * 64 + lane];
        const float o0 = y0 * c - y1 * sn;
        const float o1 = y1 * c + y0 * sn;
        y0 = o0; y1 = o1;
    }
    if (qk == 0) { y0 *= QSCALE; y1 *= QSCALE; }

    const size_t off = ((size_t)h * S_TOT + s) * HD + lane * 2;
    f16x2 hv; hv.x = (_Float16)y0; hv.y = (_Float16)y1;
    *(f16x2*)((qk ? Kh : Qh) + off) = hv;
}

// ---------------------------------------------------------------------------
// V: qkv[s][2*3072 + h*128 + d] -> transposed fp16 Vt [NH][128][S]
// ---------------------------------------------------------------------------
__global__ __launch_bounds__(256) void v_split_transpose(
    const float* __restrict__ qkv, _Float16* __restrict__ Vth)
{
    __shared__ float T[64][132];
    const int h = blockIdx.y;
    const int s0 = blockIdx.x * 64;
    const int t = threadIdx.x;
    {
        const int sl = t >> 2, dp = (t & 3) * 32;
#pragma unroll
        for (int j = 0; j < 8; ++j) {
            float4 v = *(const float4*)(qkv + (size_t)(s0 + sl) * QKV_N + 2 * DIMC + h * HD + dp + j * 4);
            *(float4*)&T[sl][dp + j * 4] = v;
        }
    }
    __syncthreads();
    const int d = t >> 1, sh = (t & 1) * 32;
    f16x8 hv[4];
#pragma unroll
    for (int ss = 0; ss < 32; ++ss)
        hv[ss >> 3][ss & 7] = (_Float16)T[sh + ss][d];
    _Float16* bh = Vth + ((size_t)h * HD + d) * S_TOT + s0 + sh;
#pragma unroll
    for (int j = 0; j < 4; ++j)
        *(f16x8*)(bh + j * 8) = hv[j];
}

// ---------------------------------------------------------------------------
// Flash attention, fp16 MFMA, log2-domain softmax, defer-max (THR=11).
// Block = (64 q, head), 4 waves x 16 q. KVBLK=64. Swapped scores K@Q^T.
// XOR-granule-swizzled LDS (conflict-free), 40KB LDS, XCD-chunked grid.
// ---------------------------------------------------------------------------
__global__ __launch_bounds__(256) void attn_mfma(
    const _Float16* __restrict__ Qg, const _Float16* __restrict__ Kg,
    const _Float16* __restrict__ Vg, _Float16* __restrict__ aoh)
{
    __shared__ __attribute__((aligned(16))) _Float16 Ksh[4 * 64 * 32]; // 16 KB
    __shared__ __attribute__((aligned(16))) _Float16 Vsh[128 * 64];    // 16 KB
    __shared__ __attribute__((aligned(16))) _Float16 Pah[4 * 16 * 64]; //  8 KB

    const int wgid = ((int)blockIdx.x & 7) * 108 + ((int)blockIdx.x >> 3);
    const int h = wgid / 36;
    const int q0 = (wgid % 36) * 64;
    const int tid = threadIdx.x;
    const int w = tid >> 6, l = tid & 63;
    const int lr = l & 15, g = l >> 4;

    const int qrow = q0 + w * 16 + lr;
    const _Float16* qb = Qg + ((size_t)h * S_TOT + qrow) * HD + g * 8;
    f16x8 qh[4];
#pragma unroll
    for (int db = 0; db < 4; ++db)
        qh[db] = *(const f16x8*)(qb + db * 32);

    f32x4 o[8] = {};
    float mrow = -3.0e38f, lrow = 0.0f;

    const int kxr = (lr >> 1) & 3;
    const int px  = lr & 7;
    int ksl[4];
#pragma unroll
    for (int db = 0; db < 4; ++db) ksl[db] = (g ^ kxr ^ db) * 8;
    const int vs0 = (g ^ px) * 8;
    const int vs1 = ((4 + g) ^ px) * 8;

    const int kkv = tid >> 2, kdb = tid & 3;
    const int vd = tid >> 1;
    const int kx = (kkv >> 1) & 3;
    const int kbase = kdb * 2048 + kkv * 32;
    const int vbase = vd * 64;
    const int vx = vd & 7;
    const int vg0 = (tid & 1) * 4;
    const _Float16* gK = Kg + ((size_t)h * S_TOT + kkv) * HD + kdb * 32;
    const _Float16* gV = Vg + ((size_t)h * HD + vd) * S_TOT + (tid & 1) * 32;

    uint4 rK0, rK1, rK2, rK3, rV0, rV1, rV2, rV3;
#define LOADKV(kv0) { \
    rK0 = *(const uint4*)(gK + (size_t)(kv0) * HD);      rK1 = *(const uint4*)(gK + (size_t)(kv0) * HD + 8); \
    rK2 = *(const uint4*)(gK + (size_t)(kv0) * HD + 16); rK3 = *(const uint4*)(gK + (size_t)(kv0) * HD + 24); \
    rV0 = *(const uint4*)(gV + (kv0));      rV1 = *(const uint4*)(gV + (kv0) + 8); \
    rV2 = *(const uint4*)(gV + (kv0) + 16); rV3 = *(const uint4*)(gV + (kv0) + 24); }

    LOADKV(0);

    for (int kb = 0; kb < S_TOT / 64; ++kb) {
        __syncthreads();
        *(uint4*)&Ksh[kbase + ((0 ^ kx ^ kdb) * 8)] = rK0;
        *(uint4*)&Ksh[kbase + ((1 ^ kx ^ kdb) * 8)] = rK1;
        *(uint4*)&Ksh[kbase + ((2 ^ kx ^ kdb) * 8)] = rK2;
        *(uint4*)&Ksh[kbase + ((3 ^ kx ^ kdb) * 8)] = rK3;
        *(uint4*)&Vsh[vbase + (((vg0 + 0) ^ vx) * 8)] = rV0;
        *(uint4*)&Vsh[vbase + (((vg0 + 1) ^ vx) * 8)] = rV1;
        *(uint4*)&Vsh[vbase + (((vg0 + 2) ^ vx) * 8)] = rV2;
        *(uint4*)&Vsh[vbase + (((vg0 + 3) ^ vx) * 8)] = rV3;
        __syncthreads();
        if (kb + 1 < S_TOT / 64) LOADKV((kb + 1) * 64);

        f32x4 sT[4] = {};
        __builtin_amdgcn_s_setprio(1);
#pragma unroll
        for (int db = 0; db < 4; ++db)
#pragma unroll
            for (int mf = 0; mf < 4; ++mf) {
                f16x8 kf = *(const f16x8*)&Ksh[db * 2048 + (mf * 16 + lr) * 32 + ksl[db]];
                sT[mf] = MFMA(kf, qh[db], sT[mf]);
            }
        __builtin_amdgcn_s_setprio(0);

        float pm = -3.0e38f;
#pragma unroll
        for (int mf = 0; mf < 4; ++mf)
#pragma unroll
            for (int e = 0; e < 4; ++e)
                pm = fmaxf(pm, sT[mf][e]);
        pm = fmaxf(pm, __shfl_xor(pm, 16, 64));
        pm = fmaxf(pm, __shfl_xor(pm, 32, 64));

        if (__any(pm > mrow + 11.0f)) {
            const float mnew = fmaxf(mrow, pm);
            const float alpha = exp2f(mrow - mnew);
            lrow *= alpha;
            mrow = mnew;
            const float a0 = __shfl(alpha, g * 4 + 0, 64);
            const float a1 = __shfl(alpha, g * 4 + 1, 64);
            const float a2 = __shfl(alpha, g * 4 + 2, 64);
            const float a3 = __shfl(alpha, g * 4 + 3, 64);
#pragma unroll
            for (int df = 0; df < 8; ++df) {
                o[df][0] *= a0; o[df][1] *= a1; o[df][2] *= a2; o[df][3] *= a3;
            }
        }

        float rs = 0.0f;
        float ex_[4][4];
#pragma unroll
        for (int mf = 0; mf < 4; ++mf)
#pragma unroll
            for (int e = 0; e < 4; ++e) {
                const float pv = exp2f(sT[mf][e] - mrow);
                ex_[mf][e] = pv;
                rs += pv;
            }
        rs += __shfl_xor(rs, 16, 64);
        rs += __shfl_xor(rs, 32, 64);
        lrow += rs;

        {
            const int pbase = w * 1024 + lr * 64;
#pragma unroll
            for (int mf = 0; mf < 4; ++mf) {
                const int slot = ((mf * 2 + (g >> 1)) ^ px) * 8 + (g & 1) * 4;
                f16x2 t0; t0.x = (_Float16)ex_[mf][0]; t0.y = (_Float16)ex_[mf][1];
                f16x2 t1; t1.x = (_Float16)ex_[mf][2]; t1.y = (_Float16)ex_[mf][3];
                *(f16x2*)&Pah[pbase + slot]     = t0;
                *(f16x2*)&Pah[pbase + slot + 2] = t1;
            }
        }

        f16x8 pa0 = *(const f16x8*)&Pah[w * 1024 + lr * 64 + vs0];
        f16x8 pa1 = *(const f16x8*)&Pah[w * 1024 + lr * 64 + vs1];
        __builtin_amdgcn_s_setprio(1);
#pragma unroll
        for (int df = 0; df < 8; ++df) {
            f16x8 vf0 = *(const f16x8*)&Vsh[(df * 16 + lr) * 64 + vs0];
            f16x8 vf1 = *(const f16x8*)&Vsh[(df * 16 + lr) * 64 + vs1];
            o[df] = MFMA(pa0, vf0, o[df]);
            o[df] = MFMA(pa1, vf1, o[df]);
        }
        __builtin_amdgcn_s_setprio(0);
    }
#undef LOADKV

    const float inv = 1.0f / lrow;
    const float b0 = __shfl(inv, g * 4 + 0, 64);
    const float b1 = __shfl(inv, g * 4 + 1, 64);
    const float b2 = __shfl(inv, g * 4 + 2, 64);
    const float b3 = __shfl(inv, g * 4 + 3, 64);
    const float bb[4] = {b0, b1, b2, b3};
#pragma unroll
    for (int df = 0; df < 8; ++df)
#pragma unroll
        for (int e = 0; e < 4; ++e) {
            const int r = q0 + w * 16 + g * 4 + e;
            aoh[(size_t)r * DIMC + h * HD + df * 16 + lr] = (_Float16)(o[df][e] * bb[e]);
        }
}

// ---------------------------------------------------------------------------
extern "C" void kernel_launch(void* const* d_in, const int* in_sizes, int n_in,
                              void* d_out, int out_size, void* d_ws, size_t ws_size,
                              hipStream_t stream)
{
    const float* hid  = (const float*)d_in[0];
    const float* enc  = (const float*)d_in[1];
    const float* cost = (const float*)d_in[2];
    const float* sint = (const float*)d_in[3];
    const float* Wqkv = (const float*)d_in[4];
    const float* bqkv = (const float*)d_in[5];
    const float* Wout = (const float*)d_in[6];
    const float* bout = (const float*)d_in[7];
    float* out = (float*)d_out;

    char* ws = (char*)d_ws;
    float*    qkv  = (float*)(ws + 0);            // 84.93 MB; dead after v_transpose
    _Float16* aoh  = (_Float16*)(ws + 0);         // attn out, over qkv
    _Float16* xh   = (_Float16*)(ws + 84934656);  // then Qh over it
    _Float16* Qh   = (_Float16*)(ws + 84934656);
    _Float16* Kh   = (_Float16*)(ws + 99090432);
    _Float16* Wth  = (_Float16*)(ws + 113246208); // full Wqkv^T hi, 56.6 MB (dead after gemm)
    _Float16* Vth  = (_Float16*)(ws + 113246208); // over Wth
    _Float16* W2h  = (_Float16*)(ws + 132120576); // 18.87 MB (after Wth dead)

    split_x<<<S_TOT, 256, 0, stream>>>(enc, hid, xh);
    transpose_w_hi<<<dim3(144, 48), 256, 0, stream>>>(Wqkv, QKV_N, Wth);
    gemm_f16_8ph<<<324, 512, 0, stream>>>(xh, Wth, bqkv, qkv);
    transpose_w_hi<<<dim3(48, 48), 256, 0, stream>>>(Wout, DIMC, W2h);
    ln_rope_split<<<(S_TOT * 48) / 4, 256, 0, stream>>>(qkv, cost, sint, Qh, Kh);
    v_split_transpose<<<dim3(36, 24), 256, 0, stream>>>(qkv, Vth);
    attn_mfma<<<864, 256, 0, stream>>>(Qh, Kh, Vth, aoh);
    gemm_f16_lds<1><<<18 * 24, 256, 0, stream>>>(aoh, W2h, bout, out, 18, DIMC);
}

// Round 9
// 411.303 us; speedup vs baseline: 1.1469x; 1.1469x over previous
//
#include <hip/hip_runtime.h>

#define DIMC 3072
#define NH 24
#define HD 128
#define QKV_N 9216
#define S_TXT 256
#define S_IMG 2048
#define S_TOT 2304

typedef _Float16 f16x8 __attribute__((ext_vector_type(8)));
typedef _Float16 f16x4 __attribute__((ext_vector_type(4)));
typedef _Float16 f16x2 __attribute__((ext_vector_type(2)));
typedef float f32x4 __attribute__((ext_vector_type(4)));

#define MFMA(A, B, C) __builtin_amdgcn_mfma_f32_16x16x32_f16(A, B, C, 0, 0, 0)

// scale(1/sqrt(128)) * log2(e): scores computed directly in log2 domain
#define QSCALE (0.08838834764831845f * 1.4426950408889634f)

// direct global->LDS async copy, 16B per lane; lds base must be wave-uniform
__device__ __forceinline__ void gl2lds16(const _Float16* g, _Float16* l) {
    __builtin_amdgcn_global_load_lds(
        (const __attribute__((address_space(1))) unsigned int*)g,
        (__attribute__((address_space(3))) unsigned int*)l,
        16, 0, 0);
}

// ---------------------------------------------------------------------------
// concat(enc,hid) -> fp16 (hi only)
// ---------------------------------------------------------------------------
__global__ __launch_bounds__(256) void split_x(
    const float* __restrict__ enc, const float* __restrict__ hid,
    _Float16* __restrict__ xh)
{
    const int s = blockIdx.x;
    const float* src = (s < S_TXT) ? enc + (size_t)s * DIMC
                                   : hid + (size_t)(s - S_TXT) * DIMC;
    const int t = threadIdx.x;
#pragma unroll
    for (int it = 0; it < 3; ++it) {
        const int i = (it * 256 + t) * 4;
        float4 v = *(const float4*)(src + i);
        f16x4 hv;
        hv.x = (_Float16)v.x; hv.y = (_Float16)v.y;
        hv.z = (_Float16)v.z; hv.w = (_Float16)v.w;
        *(f16x4*)(xh + (size_t)s * DIMC + i) = hv;
    }
}

// ---------------------------------------------------------------------------
// W [3072 k][ldw] f32 -> Wt [n][3072 k] fp16 (hi only)
// ---------------------------------------------------------------------------
__global__ __launch_bounds__(256) void transpose_w_hi(
    const float* __restrict__ W, const int ldw, _Float16* __restrict__ Th)
{
    __shared__ float T[64][68];
    const int n0 = blockIdx.x * 64, k0 = blockIdx.y * 64;
    const int t = threadIdx.x;
    {
        const int r = t >> 2, c4 = (t & 3) * 16;
#pragma unroll
        for (int j = 0; j < 4; ++j) {
            float4 v = *(const float4*)(W + (size_t)(k0 + r) * ldw + n0 + c4 + j * 4);
            *(float4*)&T[r][c4 + j * 4] = v;
        }
    }
    __syncthreads();
    const int nr = t >> 2, kp = (t & 3) * 16;
    f16x8 hv0, hv1;
#pragma unroll
    for (int j = 0; j < 8; ++j) hv0[j] = (_Float16)T[kp + j][nr];
#pragma unroll
    for (int j = 0; j < 8; ++j) hv1[j] = (_Float16)T[kp + 8 + j][nr];
    _Float16* dh = Th + (size_t)(n0 + nr) * DIMC + k0 + kp;
    *(f16x8*)(dh) = hv0; *(f16x8*)(dh + 8) = hv1;
}

// ---------------------------------------------------------------------------
// m97-structure fp16 GEMM: C = A @ B^T + bias.
// 128x128 tile, BK=32, 4 waves 2x2, global_load_lds width=16.
// T1 XCD-chunked swizzle + T2 both-sides LDS slot-XOR (0 conflicts, R6).
// ---------------------------------------------------------------------------
template <int REMAP>
__global__ __launch_bounds__(256) void gemm_f16_lds(
    const _Float16* __restrict__ Ah, const _Float16* __restrict__ Bh,
    const float* __restrict__ bias, float* __restrict__ C,
    const int nblk_m, const int ldc)
{
    __shared__ __attribute__((aligned(16))) _Float16 Ash[128 * 32];
    __shared__ __attribute__((aligned(16))) _Float16 Bsh[128 * 32];

    const int cpx = (int)gridDim.x >> 3;
    const int wgid = (blockIdx.x & 7) * cpx + (blockIdx.x >> 3);
    const int bm = (wgid % nblk_m) * 128;
    const int bn = (wgid / nblk_m) * 128;

    const int tid = threadIdx.x;
    const int l = tid & 63, w = tid >> 6;
    const int wr = w >> 1, wc = w & 1;
    const int lr = l & 15, g = l >> 4;

    const int srow0 = w * 32 + (l >> 2);
    const int srow1 = srow0 + 16;
    const int skp0 = (((l & 3) ^ ((srow0 >> 1) & 3)) * 8);
    const int skp1 = (((l & 3) ^ ((srow1 >> 1) & 3)) * 8);
    const _Float16* gA0 = Ah + (size_t)(bm + srow0) * DIMC + skp0;
    const _Float16* gA1 = Ah + (size_t)(bm + srow1) * DIMC + skp1;
    const _Float16* gB0 = Bh + (size_t)(bn + srow0) * DIMC + skp0;
    const _Float16* gB1 = Bh + (size_t)(bn + srow1) * DIMC + skp1;
    _Float16* lA0 = &Ash[(w * 32) * 32];
    _Float16* lA1 = &Ash[(w * 32 + 16) * 32];
    _Float16* lB0 = &Bsh[(w * 32) * 32];
    _Float16* lB1 = &Bsh[(w * 32 + 16) * 32];

    int aoff[4], boff[4];
#pragma unroll
    for (int i = 0; i < 4; ++i) {
        const int ra = wr * 64 + i * 16 + lr;
        const int rb = wc * 64 + i * 16 + lr;
        aoff[i] = ra * 32 + ((g ^ ((ra >> 1) & 3)) * 8);
        boff[i] = rb * 32 + ((g ^ ((rb >> 1) & 3)) * 8);
    }

    f32x4 acc[4][4] = {};

    for (int k0 = 0; k0 < DIMC; k0 += 32) {
        gl2lds16(gA0 + k0, lA0);
        gl2lds16(gA1 + k0, lA1);
        gl2lds16(gB0 + k0, lB0);
        gl2lds16(gB1 + k0, lB1);
        __syncthreads();

        f16x8 bhf[4];
#pragma unroll
        for (int ni = 0; ni < 4; ++ni)
            bhf[ni] = *(const f16x8*)&Bsh[boff[ni]];
#pragma unroll
        for (int mi = 0; mi < 4; ++mi) {
            f16x8 ahf = *(const f16x8*)&Ash[aoff[mi]];
#pragma unroll
            for (int ni = 0; ni < 4; ++ni)
                acc[mi][ni] = MFMA(ahf, bhf[ni], acc[mi][ni]);
        }
        __syncthreads();
    }

#pragma unroll
    for (int mi = 0; mi < 4; ++mi)
#pragma unroll
        for (int ni = 0; ni < 4; ++ni) {
            const int cl = bn + wc * 64 + ni * 16 + lr;
            const float bv = bias[cl];
#pragma unroll
            for (int e = 0; e < 4; ++e) {
                const int r = bm + wr * 64 + mi * 16 + g * 4 + e;
                if (REMAP) {
                    const int gr = (r < S_TXT) ? (S_IMG + r) : (r - S_TXT);
                    C[(size_t)gr * DIMC + cl] = acc[mi][ni][e] + bv;
                } else {
                    C[(size_t)r * ldc + cl] = acc[mi][ni][e] + bv;
                }
            }
        }
}

// ---------------------------------------------------------------------------
// LayerNorm + RoPE; Q is pre-scaled by scale*log2(e). fp16 out [NH][S][128].
// ---------------------------------------------------------------------------
__global__ __launch_bounds__(256) void ln_rope_split(
    const float* __restrict__ qkv,
    const float* __restrict__ cost, const float* __restrict__ sint,
    _Float16* __restrict__ Qh, _Float16* __restrict__ Kh)
{
    const int wave = threadIdx.x >> 6;
    const int lane = threadIdx.x & 63;
    const int task = blockIdx.x * 4 + wave;
    const int s = task / 48;
    const int rem = task % 48;
    const int qk = rem / 24;
    const int h = rem % 24;

    const float* p = qkv + (size_t)s * QKV_N + qk * DIMC + h * HD;
    float2 x = *(const float2*)(p + lane * 2);

    float sum = x.x + x.y;
    float sq = x.x * x.x + x.y * x.y;
#pragma unroll
    for (int off = 1; off < 64; off <<= 1) {
        sum += __shfl_xor(sum, off, 64);
        sq  += __shfl_xor(sq, off, 64);
    }
    const float mu = sum * (1.0f / 128.0f);
    const float var = sq * (1.0f / 128.0f) - mu * mu;
    const float rstd = rsqrtf(var + 1e-5f);
    float y0 = (x.x - mu) * rstd;
    float y1 = (x.y - mu) * rstd;

    if (s >= S_TXT) {
        const int ip = s - S_TXT;
        const float c = cost[ip * 64 + lane];
        const float sn = sint[ip * 64 + lane];
        const float o0 = y0 * c - y1 * sn;
        const float o1 = y1 * c + y0 * sn;
        y0 = o0; y1 = o1;
    }
    if (qk == 0) { y0 *= QSCALE; y1 *= QSCALE; }

    const size_t off = ((size_t)h * S_TOT + s) * HD + lane * 2;
    f16x2 hv; hv.x = (_Float16)y0; hv.y = (_Float16)y1;
    *(f16x2*)((qk ? Kh : Qh) + off) = hv;
}

// ---------------------------------------------------------------------------
// V: qkv[s][2*3072 + h*128 + d] -> transposed fp16 Vt [NH][128][S]
// ---------------------------------------------------------------------------
__global__ __launch_bounds__(256) void v_split_transpose(
    const float* __restrict__ qkv, _Float16* __restrict__ Vth)
{
    __shared__ float T[64][132];
    const int h = blockIdx.y;
    const int s0 = blockIdx.x * 64;
    const int t = threadIdx.x;
    {
        const int sl = t >> 2, dp = (t & 3) * 32;
#pragma unroll
        for (int j = 0; j < 8; ++j) {
            float4 v = *(const float4*)(qkv + (size_t)(s0 + sl) * QKV_N + 2 * DIMC + h * HD + dp + j * 4);
            *(float4*)&T[sl][dp + j * 4] = v;
        }
    }
    __syncthreads();
    const int d = t >> 1, sh = (t & 1) * 32;
    f16x8 hv[4];
#pragma unroll
    for (int ss = 0; ss < 32; ++ss)
        hv[ss >> 3][ss & 7] = (_Float16)T[sh + ss][d];
    _Float16* bh = Vth + ((size_t)h * HD + d) * S_TOT + s0 + sh;
#pragma unroll
    for (int j = 0; j < 4; ++j)
        *(f16x8*)(bh + j * 8) = hv[j];
}

// ---------------------------------------------------------------------------
// Flash attention, fp16 MFMA, log2-domain softmax, defer-max (THR=11).
// Block = (128 q, head), 8 waves x 16 q, 512 threads. KVBLK=64.
// Swapped scores K@Q^T. XOR-granule-swizzled LDS, 48KB.
// K/V L2 traffic halved vs QBLK=64 (attn was L2-BW-bound).
// Grid 432 = 8 XCDs x 54; each XCD owns exactly 3 heads.
// ---------------------------------------------------------------------------
__global__ __launch_bounds__(512) void attn_mfma(
    const _Float16* __restrict__ Qg, const _Float16* __restrict__ Kg,
    const _Float16* __restrict__ Vg, _Float16* __restrict__ aoh)
{
    __shared__ __attribute__((aligned(16))) _Float16 Ksh[4 * 64 * 32]; // 16 KB
    __shared__ __attribute__((aligned(16))) _Float16 Vsh[128 * 64];    // 16 KB
    __shared__ __attribute__((aligned(16))) _Float16 Pah[8 * 16 * 64]; // 16 KB

    const int wgid = ((int)blockIdx.x & 7) * 54 + ((int)blockIdx.x >> 3);
    const int h = wgid / 18;
    const int q0 = (wgid % 18) * 128;
    const int tid = threadIdx.x;
    const int w = tid >> 6, l = tid & 63;
    const int lr = l & 15, g = l >> 4;

    // Q fragments (pre-scaled by QSCALE in ln_rope_split)
    const int qrow = q0 + w * 16 + lr;
    const _Float16* qb = Qg + ((size_t)h * S_TOT + qrow) * HD + g * 8;
    f16x8 qh[4];
#pragma unroll
    for (int db = 0; db < 4; ++db)
        qh[db] = *(const f16x8*)(qb + db * 32);

    f32x4 o[8] = {};
    float mrow = -3.0e38f, lrow = 0.0f;

    // swizzled read offsets
    const int kxr = (lr >> 1) & 3;
    const int px  = lr & 7;
    int ksl[4];
#pragma unroll
    for (int db = 0; db < 4; ++db) ksl[db] = (g ^ kxr ^ db) * 8;
    const int vs0 = (g ^ px) * 8;
    const int vs1 = ((4 + g) ^ px) * 8;

    // staging (512 threads, 32B each for K and V):
    // K: thread -> kv=tid>>3, 16-halfword d-chunk kd=tid&7
    const int kkv = tid >> 3, kd = tid & 7;
    const int kdb = kd >> 1, kg0 = (kd & 1) * 2;
    const int kx = (kkv >> 1) & 3;
    const int kbase = kdb * 2048 + kkv * 32;
    // V: thread -> d=tid>>2, 16-kv chunk vh=tid&3
    const int vd = tid >> 2, vh = tid & 3;
    const int vx = vd & 7;
    const int vbase = vd * 64;
    const int vg0 = vh * 2;
    const _Float16* gK = Kg + ((size_t)h * S_TOT + kkv) * HD + kd * 16;
    const _Float16* gV = Vg + ((size_t)h * HD + vd) * S_TOT + vh * 16;

    uint4 rK0, rK1, rV0, rV1;
#define LOADKV(kv0) { \
    rK0 = *(const uint4*)(gK + (size_t)(kv0) * HD);     rK1 = *(const uint4*)(gK + (size_t)(kv0) * HD + 8); \
    rV0 = *(const uint4*)(gV + (kv0));                  rV1 = *(const uint4*)(gV + (kv0) + 8); }

    LOADKV(0);

    for (int kb = 0; kb < S_TOT / 64; ++kb) {
        __syncthreads();
        *(uint4*)&Ksh[kbase + (((kg0 + 0) ^ kx ^ kdb) * 8)] = rK0;
        *(uint4*)&Ksh[kbase + (((kg0 + 1) ^ kx ^ kdb) * 8)] = rK1;
        *(uint4*)&Vsh[vbase + (((vg0 + 0) ^ vx) * 8)] = rV0;
        *(uint4*)&Vsh[vbase + (((vg0 + 1) ^ vx) * 8)] = rV1;
        __syncthreads();
        if (kb + 1 < S_TOT / 64) LOADKV((kb + 1) * 64);

        // scores S^T: 4 frags (16 kv x 16 q), log2 domain
        f32x4 sT[4] = {};
        __builtin_amdgcn_s_setprio(1);
#pragma unroll
        for (int db = 0; db < 4; ++db)
#pragma unroll
            for (int mf = 0; mf < 4; ++mf) {
                f16x8 kf = *(const f16x8*)&Ksh[db * 2048 + (mf * 16 + lr) * 32 + ksl[db]];
                sT[mf] = MFMA(kf, qh[db], sT[mf]);
            }
        __builtin_amdgcn_s_setprio(0);

        // per-lane max over this tile's 16 kv values (q = lr)
        float pm = -3.0e38f;
#pragma unroll
        for (int mf = 0; mf < 4; ++mf)
#pragma unroll
            for (int e = 0; e < 4; ++e)
                pm = fmaxf(pm, sT[mf][e]);
        pm = fmaxf(pm, __shfl_xor(pm, 16, 64));
        pm = fmaxf(pm, __shfl_xor(pm, 32, 64));

        // defer-max: rescale only when max grew by > 11 (log2 domain)
        if (__any(pm > mrow + 11.0f)) {
            const float mnew = fmaxf(mrow, pm);
            const float alpha = exp2f(mrow - mnew);
            lrow *= alpha;
            mrow = mnew;
            const float a0 = __shfl(alpha, g * 4 + 0, 64);
            const float a1 = __shfl(alpha, g * 4 + 1, 64);
            const float a2 = __shfl(alpha, g * 4 + 2, 64);
            const float a3 = __shfl(alpha, g * 4 + 3, 64);
#pragma unroll
            for (int df = 0; df < 8; ++df) {
                o[df][0] *= a0; o[df][1] *= a1; o[df][2] *= a2; o[df][3] *= a3;
            }
        }

        float rs = 0.0f;
        float ex_[4][4];
#pragma unroll
        for (int mf = 0; mf < 4; ++mf)
#pragma unroll
            for (int e = 0; e < 4; ++e) {
                const float pv = exp2f(sT[mf][e] - mrow);
                ex_[mf][e] = pv;
                rs += pv;
            }
        rs += __shfl_xor(rs, 16, 64);
        rs += __shfl_xor(rs, 32, 64);
        lrow += rs;

        // publish P into per-wave swizzled LDS slice (granule ^ (q&7))
        {
            const int pbase = w * 1024 + lr * 64;
#pragma unroll
            for (int mf = 0; mf < 4; ++mf) {
                const int slot = ((mf * 2 + (g >> 1)) ^ px) * 8 + (g & 1) * 4;
                f16x2 t0; t0.x = (_Float16)ex_[mf][0]; t0.y = (_Float16)ex_[mf][1];
                f16x2 t1; t1.x = (_Float16)ex_[mf][2]; t1.y = (_Float16)ex_[mf][3];
                *(f16x2*)&Pah[pbase + slot]     = t0;
                *(f16x2*)&Pah[pbase + slot + 2] = t1;
            }
        }

        // PV: O(16q x 128d) += P(16x64) @ V(64x128)
        f16x8 pa0 = *(const f16x8*)&Pah[w * 1024 + lr * 64 + vs0];
        f16x8 pa1 = *(const f16x8*)&Pah[w * 1024 + lr * 64 + vs1];
        __builtin_amdgcn_s_setprio(1);
#pragma unroll
        for (int df = 0; df < 8; ++df) {
            f16x8 vf0 = *(const f16x8*)&Vsh[(df * 16 + lr) * 64 + vs0];
            f16x8 vf1 = *(const f16x8*)&Vsh[(df * 16 + lr) * 64 + vs1];
            o[df] = MFMA(pa0, vf0, o[df]);
            o[df] = MFMA(pa1, vf1, o[df]);
        }
        __builtin_amdgcn_s_setprio(0);
    }
#undef LOADKV

    const float inv = 1.0f / lrow;
    const float b0 = __shfl(inv, g * 4 + 0, 64);
    const float b1 = __shfl(inv, g * 4 + 1, 64);
    const float b2 = __shfl(inv, g * 4 + 2, 64);
    const float b3 = __shfl(inv, g * 4 + 3, 64);
    const float bb[4] = {b0, b1, b2, b3};
#pragma unroll
    for (int df = 0; df < 8; ++df)
#pragma unroll
        for (int e = 0; e < 4; ++e) {
            const int r = q0 + w * 16 + g * 4 + e;
            aoh[(size_t)r * DIMC + h * HD + df * 16 + lr] = (_Float16)(o[df][e] * bb[e]);
        }
}

// ---------------------------------------------------------------------------
extern "C" void kernel_launch(void* const* d_in, const int* in_sizes, int n_in,
                              void* d_out, int out_size, void* d_ws, size_t ws_size,
                              hipStream_t stream)
{
    const float* hid  = (const float*)d_in[0];
    const float* enc  = (const float*)d_in[1];
    const float* cost = (const float*)d_in[2];
    const float* sint = (const float*)d_in[3];
    const float* Wqkv = (const float*)d_in[4];
    const float* bqkv = (const float*)d_in[5];
    const float* Wout = (const float*)d_in[6];
    const float* bout = (const float*)d_in[7];
    float* out = (float*)d_out;

    char* ws = (char*)d_ws;
    float*    qkv  = (float*)(ws + 0);            // 84.93 MB; dead after v_transpose
    _Float16* aoh  = (_Float16*)(ws + 0);         // attn out, over qkv
    _Float16* xh   = (_Float16*)(ws + 84934656);  // then Qh over it
    _Float16* Qh   = (_Float16*)(ws + 84934656);
    _Float16* Kh   = (_Float16*)(ws + 99090432);
    _Float16* Wth  = (_Float16*)(ws + 113246208); // full Wqkv^T hi, 56.6 MB (dead after gemm)
    _Float16* Vth  = (_Float16*)(ws + 113246208); // over Wth
    _Float16* W2h  = (_Float16*)(ws + 132120576); // 18.87 MB (after Wth dead)

    split_x<<<S_TOT, 256, 0, stream>>>(enc, hid, xh);
    transpose_w_hi<<<dim3(144, 48), 256, 0, stream>>>(Wqkv, QKV_N, Wth);
    gemm_f16_lds<0><<<18 * 72, 256, 0, stream>>>(xh, Wth, bqkv, qkv, 18, QKV_N);
    transpose_w_hi<<<dim3(48, 48), 256, 0, stream>>>(Wout, DIMC, W2h);
    ln_rope_split<<<(S_TOT * 48) / 4, 256, 0, stream>>>(qkv, cost, sint, Qh, Kh);
    v_split_transpose<<<dim3(36, 24), 256, 0, stream>>>(qkv, Vth);
    attn_mfma<<<432, 512, 0, stream>>>(Qh, Kh, Vth, aoh);
    gemm_f16_lds<1><<<18 * 24, 256, 0, stream>>>(aoh, W2h, bout, out, 18, DIMC);
}

// Round 10
// 399.718 us; speedup vs baseline: 1.1802x; 1.0290x over previous
//
#include <hip/hip_runtime.h>

#define DIMC 3072
#define NH 24
#define HD 128
#define QKV_N 9216
#define S_TXT 256
#define S_IMG 2048
#define S_TOT 2304

typedef _Float16 f16x8 __attribute__((ext_vector_type(8)));
typedef _Float16 f16x4 __attribute__((ext_vector_type(4)));
typedef _Float16 f16x2 __attribute__((ext_vector_type(2)));
typedef float f32x4 __attribute__((ext_vector_type(4)));

#define MFMA(A, B, C) __builtin_amdgcn_mfma_f32_16x16x32_f16(A, B, C, 0, 0, 0)

// scale(1/sqrt(128)) * log2(e): scores computed directly in log2 domain
#define QSCALE (0.08838834764831845f * 1.4426950408889634f)

// direct global->LDS async copy, 16B per lane; lds base must be wave-uniform
__device__ __forceinline__ void gl2lds16(const _Float16* g, _Float16* l) {
    __builtin_amdgcn_global_load_lds(
        (const __attribute__((address_space(1))) unsigned int*)g,
        (__attribute__((address_space(3))) unsigned int*)l,
        16, 0, 0);
}

// ---------------------------------------------------------------------------
// concat(enc,hid) -> fp16 (hi only)
// ---------------------------------------------------------------------------
__global__ __launch_bounds__(256) void split_x(
    const float* __restrict__ enc, const float* __restrict__ hid,
    _Float16* __restrict__ xh)
{
    const int s = blockIdx.x;
    const float* src = (s < S_TXT) ? enc + (size_t)s * DIMC
                                   : hid + (size_t)(s - S_TXT) * DIMC;
    const int t = threadIdx.x;
#pragma unroll
    for (int it = 0; it < 3; ++it) {
        const int i = (it * 256 + t) * 4;
        float4 v = *(const float4*)(src + i);
        f16x4 hv;
        hv.x = (_Float16)v.x; hv.y = (_Float16)v.y;
        hv.z = (_Float16)v.z; hv.w = (_Float16)v.w;
        *(f16x4*)(xh + (size_t)s * DIMC + i) = hv;
    }
}

// ---------------------------------------------------------------------------
// W [3072 k][ldw] f32 -> Wt [n][3072 k] fp16 (hi only)
// ---------------------------------------------------------------------------
__global__ __launch_bounds__(256) void transpose_w_hi(
    const float* __restrict__ W, const int ldw, _Float16* __restrict__ Th)
{
    __shared__ float T[64][68];
    const int n0 = blockIdx.x * 64, k0 = blockIdx.y * 64;
    const int t = threadIdx.x;
    {
        const int r = t >> 2, c4 = (t & 3) * 16;
#pragma unroll
        for (int j = 0; j < 4; ++j) {
            float4 v = *(const float4*)(W + (size_t)(k0 + r) * ldw + n0 + c4 + j * 4);
            *(float4*)&T[r][c4 + j * 4] = v;
        }
    }
    __syncthreads();
    const int nr = t >> 2, kp = (t & 3) * 16;
    f16x8 hv0, hv1;
#pragma unroll
    for (int j = 0; j < 8; ++j) hv0[j] = (_Float16)T[kp + j][nr];
#pragma unroll
    for (int j = 0; j < 8; ++j) hv1[j] = (_Float16)T[kp + 8 + j][nr];
    _Float16* dh = Th + (size_t)(n0 + nr) * DIMC + k0 + kp;
    *(f16x8*)(dh) = hv0; *(f16x8*)(dh + 8) = hv1;
}

// ---------------------------------------------------------------------------
// QKV GEMM with fused output layout: C tile (128 s x 128 d, one head) is
// written fp16 directly to per-head consumer layouts:
//   type 0/1 (q/k): raw [NH][S][128]  (LN+RoPE applied in-place later)
//   type 2   (v) : transposed [NH][128][S]  (f16x4: 4 consecutive s/lane)
// Core: 128x128 tile, BK=32, 4 waves 2x2, global_load_lds w16,
// T1 XCD-chunked swizzle + T2 both-sides slot-XOR (0 conflicts, R6).
// ---------------------------------------------------------------------------
__global__ __launch_bounds__(256) void gemm_qkv(
    const _Float16* __restrict__ Ah, const _Float16* __restrict__ Bh,
    const float* __restrict__ bias,
    _Float16* __restrict__ Qh, _Float16* __restrict__ Kh,
    _Float16* __restrict__ Vt)
{
    __shared__ __attribute__((aligned(16))) _Float16 Ash[128 * 32];
    __shared__ __attribute__((aligned(16))) _Float16 Bsh[128 * 32];

    const int cpx = (int)gridDim.x >> 3;
    const int wgid = (blockIdx.x & 7) * cpx + (blockIdx.x >> 3);
    const int bm = (wgid % 18) * 128;
    const int bn = (wgid / 18) * 128;

    const int tid = threadIdx.x;
    const int l = tid & 63, w = tid >> 6;
    const int wr = w >> 1, wc = w & 1;
    const int lr = l & 15, g = l >> 4;

    const int srow0 = w * 32 + (l >> 2);
    const int srow1 = srow0 + 16;
    const int skp0 = (((l & 3) ^ ((srow0 >> 1) & 3)) * 8);
    const int skp1 = (((l & 3) ^ ((srow1 >> 1) & 3)) * 8);
    const _Float16* gA0 = Ah + (size_t)(bm + srow0) * DIMC + skp0;
    const _Float16* gA1 = Ah + (size_t)(bm + srow1) * DIMC + skp1;
    const _Float16* gB0 = Bh + (size_t)(bn + srow0) * DIMC + skp0;
    const _Float16* gB1 = Bh + (size_t)(bn + srow1) * DIMC + skp1;
    _Float16* lA0 = &Ash[(w * 32) * 32];
    _Float16* lA1 = &Ash[(w * 32 + 16) * 32];
    _Float16* lB0 = &Bsh[(w * 32) * 32];
    _Float16* lB1 = &Bsh[(w * 32 + 16) * 32];

    int aoff[4], boff[4];
#pragma unroll
    for (int i = 0; i < 4; ++i) {
        const int ra = wr * 64 + i * 16 + lr;
        const int rb = wc * 64 + i * 16 + lr;
        aoff[i] = ra * 32 + ((g ^ ((ra >> 1) & 3)) * 8);
        boff[i] = rb * 32 + ((g ^ ((rb >> 1) & 3)) * 8);
    }

    f32x4 acc[4][4] = {};

    for (int k0 = 0; k0 < DIMC; k0 += 32) {
        gl2lds16(gA0 + k0, lA0);
        gl2lds16(gA1 + k0, lA1);
        gl2lds16(gB0 + k0, lB0);
        gl2lds16(gB1 + k0, lB1);
        __syncthreads();

        f16x8 bhf[4];
#pragma unroll
        for (int ni = 0; ni < 4; ++ni)
            bhf[ni] = *(const f16x8*)&Bsh[boff[ni]];
#pragma unroll
        for (int mi = 0; mi < 4; ++mi) {
            f16x8 ahf = *(const f16x8*)&Ash[aoff[mi]];
#pragma unroll
            for (int ni = 0; ni < 4; ++ni)
                acc[mi][ni] = MFMA(ahf, bhf[ni], acc[mi][ni]);
        }
        __syncthreads();
    }

    // fused epilogue: type/head from the n-block (128-wide = one head)
    const int nb = bn >> 7;          // 0..71
    const int typ = nb / NH;         // 0=q 1=k 2=v  (uniform per block)
    const int h = nb % NH;

    if (typ == 2) {
        // V transposed: Vt[h][d][s], 4 consecutive s per lane -> f16x4
#pragma unroll
        for (int mi = 0; mi < 4; ++mi) {
            const int sbase = bm + wr * 64 + mi * 16 + g * 4;
#pragma unroll
            for (int ni = 0; ni < 4; ++ni) {
                const int col = wc * 64 + ni * 16 + lr;
                const float bv = bias[bn + col];
                f16x4 vv;
                vv.x = (_Float16)(acc[mi][ni][0] + bv);
                vv.y = (_Float16)(acc[mi][ni][1] + bv);
                vv.z = (_Float16)(acc[mi][ni][2] + bv);
                vv.w = (_Float16)(acc[mi][ni][3] + bv);
                *(f16x4*)&Vt[((size_t)h * HD + col) * S_TOT + sbase] = vv;
            }
        }
    } else {
        _Float16* dst = (typ ? Kh : Qh) + (size_t)h * S_TOT * HD;
#pragma unroll
        for (int mi = 0; mi < 4; ++mi)
#pragma unroll
            for (int ni = 0; ni < 4; ++ni) {
                const int col = wc * 64 + ni * 16 + lr;
                const float bv = bias[bn + col];
#pragma unroll
                for (int e = 0; e < 4; ++e) {
                    const int r = bm + wr * 64 + mi * 16 + g * 4 + e;
                    dst[(size_t)r * HD + col] = (_Float16)(acc[mi][ni][e] + bv);
                }
            }
    }
}

// ---------------------------------------------------------------------------
// m97-structure fp16 GEMM (out-proj): C = A @ B^T + bias, remapped rows.
// ---------------------------------------------------------------------------
template <int REMAP>
__global__ __launch_bounds__(256) void gemm_f16_lds(
    const _Float16* __restrict__ Ah, const _Float16* __restrict__ Bh,
    const float* __restrict__ bias, float* __restrict__ C,
    const int nblk_m, const int ldc)
{
    __shared__ __attribute__((aligned(16))) _Float16 Ash[128 * 32];
    __shared__ __attribute__((aligned(16))) _Float16 Bsh[128 * 32];

    const int cpx = (int)gridDim.x >> 3;
    const int wgid = (blockIdx.x & 7) * cpx + (blockIdx.x >> 3);
    const int bm = (wgid % nblk_m) * 128;
    const int bn = (wgid / nblk_m) * 128;

    const int tid = threadIdx.x;
    const int l = tid & 63, w = tid >> 6;
    const int wr = w >> 1, wc = w & 1;
    const int lr = l & 15, g = l >> 4;

    const int srow0 = w * 32 + (l >> 2);
    const int srow1 = srow0 + 16;
    const int skp0 = (((l & 3) ^ ((srow0 >> 1) & 3)) * 8);
    const int skp1 = (((l & 3) ^ ((srow1 >> 1) & 3)) * 8);
    const _Float16* gA0 = Ah + (size_t)(bm + srow0) * DIMC + skp0;
    const _Float16* gA1 = Ah + (size_t)(bm + srow1) * DIMC + skp1;
    const _Float16* gB0 = Bh + (size_t)(bn + srow0) * DIMC + skp0;
    const _Float16* gB1 = Bh + (size_t)(bn + srow1) * DIMC + skp1;
    _Float16* lA0 = &Ash[(w * 32) * 32];
    _Float16* lA1 = &Ash[(w * 32 + 16) * 32];
    _Float16* lB0 = &Bsh[(w * 32) * 32];
    _Float16* lB1 = &Bsh[(w * 32 + 16) * 32];

    int aoff[4], boff[4];
#pragma unroll
    for (int i = 0; i < 4; ++i) {
        const int ra = wr * 64 + i * 16 + lr;
        const int rb = wc * 64 + i * 16 + lr;
        aoff[i] = ra * 32 + ((g ^ ((ra >> 1) & 3)) * 8);
        boff[i] = rb * 32 + ((g ^ ((rb >> 1) & 3)) * 8);
    }

    f32x4 acc[4][4] = {};

    for (int k0 = 0; k0 < DIMC; k0 += 32) {
        gl2lds16(gA0 + k0, lA0);
        gl2lds16(gA1 + k0, lA1);
        gl2lds16(gB0 + k0, lB0);
        gl2lds16(gB1 + k0, lB1);
        __syncthreads();

        f16x8 bhf[4];
#pragma unroll
        for (int ni = 0; ni < 4; ++ni)
            bhf[ni] = *(const f16x8*)&Bsh[boff[ni]];
#pragma unroll
        for (int mi = 0; mi < 4; ++mi) {
            f16x8 ahf = *(const f16x8*)&Ash[aoff[mi]];
#pragma unroll
            for (int ni = 0; ni < 4; ++ni)
                acc[mi][ni] = MFMA(ahf, bhf[ni], acc[mi][ni]);
        }
        __syncthreads();
    }

#pragma unroll
    for (int mi = 0; mi < 4; ++mi)
#pragma unroll
        for (int ni = 0; ni < 4; ++ni) {
            const int cl = bn + wc * 64 + ni * 16 + lr;
            const float bv = bias[cl];
#pragma unroll
            for (int e = 0; e < 4; ++e) {
                const int r = bm + wr * 64 + mi * 16 + g * 4 + e;
                if (REMAP) {
                    const int gr = (r < S_TXT) ? (S_IMG + r) : (r - S_TXT);
                    C[(size_t)gr * DIMC + cl] = acc[mi][ni][e] + bv;
                } else {
                    C[(size_t)r * ldc + cl] = acc[mi][ni][e] + bv;
                }
            }
        }
}

// ---------------------------------------------------------------------------
// In-place LayerNorm + RoPE on fp16 Q/K rows [NH][S][128]; Q pre-scaled by
// QSCALE. One wave per (s, q/k, head) row; fully coalesced f16x2 loads.
// ---------------------------------------------------------------------------
__global__ __launch_bounds__(256) void ln_rope_inplace(
    _Float16* __restrict__ Qh, _Float16* __restrict__ Kh,
    const float* __restrict__ cost, const float* __restrict__ sint)
{
    const int wave = threadIdx.x >> 6;
    const int lane = threadIdx.x & 63;
    const int task = blockIdx.x * 4 + wave;
    const int s = task / 48;
    const int rem = task % 48;
    const int qk = rem / 24;
    const int h = rem % 24;

    _Float16* p = (qk ? Kh : Qh) + ((size_t)h * S_TOT + s) * HD + lane * 2;
    f16x2 xv = *(const f16x2*)p;
    float x0 = (float)xv.x, x1 = (float)xv.y;

    float sum = x0 + x1;
    float sq = x0 * x0 + x1 * x1;
#pragma unroll
    for (int off = 1; off < 64; off <<= 1) {
        sum += __shfl_xor(sum, off, 64);
        sq  += __shfl_xor(sq, off, 64);
    }
    const float mu = sum * (1.0f / 128.0f);
    const float var = sq * (1.0f / 128.0f) - mu * mu;
    const float rstd = rsqrtf(var + 1e-5f);
    float y0 = (x0 - mu) * rstd;
    float y1 = (x1 - mu) * rstd;

    if (s >= S_TXT) {
        const int ip = s - S_TXT;
        const float c = cost[ip * 64 + lane];
        const float sn = sint[ip * 64 + lane];
        const float o0 = y0 * c - y1 * sn;
        const float o1 = y1 * c + y0 * sn;
        y0 = o0; y1 = o1;
    }
    if (qk == 0) { y0 *= QSCALE; y1 *= QSCALE; }

    f16x2 hv; hv.x = (_Float16)y0; hv.y = (_Float16)y1;
    *(f16x2*)p = hv;
}

// ---------------------------------------------------------------------------
// Flash attention, fp16 MFMA, log2-domain softmax, defer-max (THR=11).
// Block = (128 q, head), 8 waves x 16 q, 512 threads. KVBLK=64.
// Swapped scores K@Q^T. XOR-granule-swizzled LDS, 48KB.
// Grid 432 = 8 XCDs x 54; each XCD owns exactly 3 heads.
// ---------------------------------------------------------------------------
__global__ __launch_bounds__(512) void attn_mfma(
    const _Float16* __restrict__ Qg, const _Float16* __restrict__ Kg,
    const _Float16* __restrict__ Vg, _Float16* __restrict__ aoh)
{
    __shared__ __attribute__((aligned(16))) _Float16 Ksh[4 * 64 * 32]; // 16 KB
    __shared__ __attribute__((aligned(16))) _Float16 Vsh[128 * 64];    // 16 KB
    __shared__ __attribute__((aligned(16))) _Float16 Pah[8 * 16 * 64]; // 16 KB

    const int wgid = ((int)blockIdx.x & 7) * 54 + ((int)blockIdx.x >> 3);
    const int h = wgid / 18;
    const int q0 = (wgid % 18) * 128;
    const int tid = threadIdx.x;
    const int w = tid >> 6, l = tid & 63;
    const int lr = l & 15, g = l >> 4;

    const int qrow = q0 + w * 16 + lr;
    const _Float16* qb = Qg + ((size_t)h * S_TOT + qrow) * HD + g * 8;
    f16x8 qh[4];
#pragma unroll
    for (int db = 0; db < 4; ++db)
        qh[db] = *(const f16x8*)(qb + db * 32);

    f32x4 o[8] = {};
    float mrow = -3.0e38f, lrow = 0.0f;

    const int kxr = (lr >> 1) & 3;
    const int px  = lr & 7;
    int ksl[4];
#pragma unroll
    for (int db = 0; db < 4; ++db) ksl[db] = (g ^ kxr ^ db) * 8;
    const int vs0 = (g ^ px) * 8;
    const int vs1 = ((4 + g) ^ px) * 8;

    const int kkv = tid >> 3, kd = tid & 7;
    const int kdb = kd >> 1, kg0 = (kd & 1) * 2;
    const int kx = (kkv >> 1) & 3;
    const int kbase = kdb * 2048 + kkv * 32;
    const int vd = tid >> 2, vh = tid & 3;
    const int vx = vd & 7;
    const int vbase = vd * 64;
    const int vg0 = vh * 2;
    const _Float16* gK = Kg + ((size_t)h * S_TOT + kkv) * HD + kd * 16;
    const _Float16* gV = Vg + ((size_t)h * HD + vd) * S_TOT + vh * 16;

    uint4 rK0, rK1, rV0, rV1;
#define LOADKV(kv0) { \
    rK0 = *(const uint4*)(gK + (size_t)(kv0) * HD);     rK1 = *(const uint4*)(gK + (size_t)(kv0) * HD + 8); \
    rV0 = *(const uint4*)(gV + (kv0));                  rV1 = *(const uint4*)(gV + (kv0) + 8); }

    LOADKV(0);

    for (int kb = 0; kb < S_TOT / 64; ++kb) {
        __syncthreads();
        *(uint4*)&Ksh[kbase + (((kg0 + 0) ^ kx ^ kdb) * 8)] = rK0;
        *(uint4*)&Ksh[kbase + (((kg0 + 1) ^ kx ^ kdb) * 8)] = rK1;
        *(uint4*)&Vsh[vbase + (((vg0 + 0) ^ vx) * 8)] = rV0;
        *(uint4*)&Vsh[vbase + (((vg0 + 1) ^ vx) * 8)] = rV1;
        __syncthreads();
        if (kb + 1 < S_TOT / 64) LOADKV((kb + 1) * 64);

        f32x4 sT[4] = {};
        __builtin_amdgcn_s_setprio(1);
#pragma unroll
        for (int db = 0; db < 4; ++db)
#pragma unroll
            for (int mf = 0; mf < 4; ++mf) {
                f16x8 kf = *(const f16x8*)&Ksh[db * 2048 + (mf * 16 + lr) * 32 + ksl[db]];
                sT[mf] = MFMA(kf, qh[db], sT[mf]);
            }
        __builtin_amdgcn_s_setprio(0);

        float pm = -3.0e38f;
#pragma unroll
        for (int mf = 0; mf < 4; ++mf)
#pragma unroll
            for (int e = 0; e < 4; ++e)
                pm = fmaxf(pm, sT[mf][e]);
        pm = fmaxf(pm, __shfl_xor(pm, 16, 64));
        pm = fmaxf(pm, __shfl_xor(pm, 32, 64));

        if (__any(pm > mrow + 11.0f)) {
            const float mnew = fmaxf(mrow, pm);
            const float alpha = exp2f(mrow - mnew);
            lrow *= alpha;
            mrow = mnew;
            const float a0 = __shfl(alpha, g * 4 + 0, 64);
            const float a1 = __shfl(alpha, g * 4 + 1, 64);
            const float a2 = __shfl(alpha, g * 4 + 2, 64);
            const float a3 = __shfl(alpha, g * 4 + 3, 64);
#pragma unroll
            for (int df = 0; df < 8; ++df) {
                o[df][0] *= a0; o[df][1] *= a1; o[df][2] *= a2; o[df][3] *= a3;
            }
        }

        float rs = 0.0f;
        float ex_[4][4];
#pragma unroll
        for (int mf = 0; mf < 4; ++mf)
#pragma unroll
            for (int e = 0; e < 4; ++e) {
                const float pv = exp2f(sT[mf][e] - mrow);
                ex_[mf][e] = pv;
                rs += pv;
            }
        rs += __shfl_xor(rs, 16, 64);
        rs += __shfl_xor(rs, 32, 64);
        lrow += rs;

        {
            const int pbase = w * 1024 + lr * 64;
#pragma unroll
            for (int mf = 0; mf < 4; ++mf) {
                const int slot = ((mf * 2 + (g >> 1)) ^ px) * 8 + (g & 1) * 4;
                f16x2 t0; t0.x = (_Float16)ex_[mf][0]; t0.y = (_Float16)ex_[mf][1];
                f16x2 t1; t1.x = (_Float16)ex_[mf][2]; t1.y = (_Float16)ex_[mf][3];
                *(f16x2*)&Pah[pbase + slot]     = t0;
                *(f16x2*)&Pah[pbase + slot + 2] = t1;
            }
        }

        f16x8 pa0 = *(const f16x8*)&Pah[w * 1024 + lr * 64 + vs0];
        f16x8 pa1 = *(const f16x8*)&Pah[w * 1024 + lr * 64 + vs1];
        __builtin_amdgcn_s_setprio(1);
#pragma unroll
        for (int df = 0; df < 8; ++df) {
            f16x8 vf0 = *(const f16x8*)&Vsh[(df * 16 + lr) * 64 + vs0];
            f16x8 vf1 = *(const f16x8*)&Vsh[(df * 16 + lr) * 64 + vs1];
            o[df] = MFMA(pa0, vf0, o[df]);
            o[df] = MFMA(pa1, vf1, o[df]);
        }
        __builtin_amdgcn_s_setprio(0);
    }
#undef LOADKV

    const float inv = 1.0f / lrow;
    const float b0 = __shfl(inv, g * 4 + 0, 64);
    const float b1 = __shfl(inv, g * 4 + 1, 64);
    const float b2 = __shfl(inv, g * 4 + 2, 64);
    const float b3 = __shfl(inv, g * 4 + 3, 64);
    const float bb[4] = {b0, b1, b2, b3};
#pragma unroll
    for (int df = 0; df < 8; ++df)
#pragma unroll
        for (int e = 0; e < 4; ++e) {
            const int r = q0 + w * 16 + g * 4 + e;
            aoh[(size_t)r * DIMC + h * HD + df * 16 + lr] = (_Float16)(o[df][e] * bb[e]);
        }
}

// ---------------------------------------------------------------------------
extern "C" void kernel_launch(void* const* d_in, const int* in_sizes, int n_in,
                              void* d_out, int out_size, void* d_ws, size_t ws_size,
                              hipStream_t stream)
{
    const float* hid  = (const float*)d_in[0];
    const float* enc  = (const float*)d_in[1];
    const float* cost = (const float*)d_in[2];
    const float* sint = (const float*)d_in[3];
    const float* Wqkv = (const float*)d_in[4];
    const float* bqkv = (const float*)d_in[5];
    const float* Wout = (const float*)d_in[6];
    const float* bout = (const float*)d_in[7];
    float* out = (float*)d_out;

    char* ws = (char*)d_ws;
    _Float16* Qh  = (_Float16*)(ws + 0);          // 14.16 MB [NH][S][128]
    _Float16* Kh  = (_Float16*)(ws + 14155776);   // 14.16 MB
    _Float16* Vth = (_Float16*)(ws + 28311552);   // 14.16 MB [NH][128][S]
    _Float16* aoh = (_Float16*)(ws + 42467328);   // 14.16 MB [S][3072]
    _Float16* xh  = (_Float16*)(ws + 56623104);   // 14.16 MB
    _Float16* Wth = (_Float16*)(ws + 70778880);   // 56.62 MB Wqkv^T fp16
    _Float16* W2h = (_Float16*)(ws + 127401984);  // 18.87 MB Wout^T fp16

    split_x<<<S_TOT, 256, 0, stream>>>(enc, hid, xh);
    transpose_w_hi<<<dim3(144, 48), 256, 0, stream>>>(Wqkv, QKV_N, Wth);
    gemm_qkv<<<18 * 72, 256, 0, stream>>>(xh, Wth, bqkv, Qh, Kh, Vth);
    transpose_w_hi<<<dim3(48, 48), 256, 0, stream>>>(Wout, DIMC, W2h);
    ln_rope_inplace<<<(S_TOT * 48) / 4, 256, 0, stream>>>(Qh, Kh, cost, sint);
    attn_mfma<<<432, 512, 0, stream>>>(Qh, Kh, Vth, aoh);
    gemm_f16_lds<1><<<18 * 24, 256, 0, stream>>>(aoh, W2h, bout, out, 18, DIMC);
}